// Round 4
// baseline (1107.975 us; speedup 1.0000x reference)
//
#include <hip/hip_runtime.h>
#include <stdint.h>

#define BATCH   32768
#define NSUP    256
#define NSUB    1024
#define LATENT  512
#define NOUT    200
#define SUP_OFF ((size_t)BATCH * NOUT)  // sup_out offset in d_out
#define TOTAL_B 3088                    // 3072 gemm blocks + 16 sup blocks

typedef unsigned short u16;
typedef __attribute__((ext_vector_type(8))) __bf16 bf16x8;
typedef __attribute__((ext_vector_type(4))) float  floatx4;

typedef const __attribute__((address_space(1))) void* gptr_t;
typedef __attribute__((address_space(3))) void* sptr_t;

__device__ __forceinline__ void gload16(const void* g, void* l) {
  __builtin_amdgcn_global_load_lds((gptr_t)g, (sptr_t)l, 16, 0, 0);
}

__device__ __forceinline__ floatx4 mfma_bf16(bf16x8 a, bf16x8 b, floatx4 c) {
  return __builtin_amdgcn_mfma_f32_16x16x32_bf16(a, b, c, 0, 0, 0);
}

__device__ __forceinline__ u16 f2bf(float f) {
  unsigned int u = __float_as_uint(f);
  u += 0x7FFFu + ((u >> 16) & 1u);   // RNE; inputs finite
  return (u16)(u >> 16);
}

// =================== KERNEL 1: all preprocessing, one launch ===================
// bx 0          : sc/cc for 400 outputs (recomputes 1280 row norms into LDS -> no dep)
// bx [1,8192]   : x rows -> xb bf16 + xxb norms (4 rows/block)
// bx [8193,8512]: sup/sub rows -> sups/subs bf16 + xxsup/yys norms
// bx [8513,8640]: Mt[o][k] = -2 sum_j W[o,j] P[j,k]  (verified round-3 code)
// bx [8641,8777]: init 35072 min-slots to +inf
// bx 8778       : zero out4 + done counter
__global__ __launch_bounds__(256) void k_prep(const float* __restrict__ x,
    const float* __restrict__ sup, const float* __restrict__ sub,
    const float* __restrict__ W1, const float* __restrict__ b1,
    const float* __restrict__ W2, const float* __restrict__ b2,
    u16* __restrict__ xb, float* __restrict__ xxb,
    u16* __restrict__ sups, u16* __restrict__ subs,
    float* __restrict__ xxsup, float* __restrict__ yys,
    u16* __restrict__ Mt, float* __restrict__ sc, float* __restrict__ cc,
    unsigned int* __restrict__ minbuf, float* __restrict__ out4,
    unsigned int* __restrict__ done) {
  __shared__ float shmem[8 * 1024];
  int bx = blockIdx.x, t = threadIdx.x;
  int wave = t >> 6, lane = t & 63;

  if (bx == 0) {
    // ---- self-contained sc/cc: norms of sub(1024)+sup(256) into LDS, then dots
    float* yyl = shmem;            // [1024]
    float* xxl = shmem + 1024;     // [256]
    for (int R = wave; R < 1280; R += 4) {
      const float* src = (R < 1024) ? sub + (size_t)R * LATENT
                                    : sup + (size_t)(R - 1024) * LATENT;
      const float4* s4 = (const float4*)src + lane * 2;
      float4 a = s4[0], b = s4[1];
      float ss = a.x*a.x + a.y*a.y + a.z*a.z + a.w*a.w
               + b.x*b.x + b.y*b.y + b.z*b.z + b.w*b.w;
      for (int off = 32; off; off >>= 1) ss += __shfl_down(ss, off);
      if (lane == 0) { if (R < 1024) yyl[R] = ss; else xxl[R - 1024] = ss; }
    }
    __syncthreads();
    for (int o = wave; o < 400; o += 4) {
      int n; const float* Wr; const float* yy; float bb;
      if (o < 200) { n = NSUP; Wr = W1 + (size_t)o * NSUP; yy = xxl; bb = b1[o]; }
      else         { n = NSUB; Wr = W2 + (size_t)(o - 200) * NSUB; yy = yyl; bb = b2[o - 200]; }
      float s = 0.f, c = 0.f;
      for (int j = lane; j < n; j += 64) { float w = Wr[j]; s += w; c += w * yy[j]; }
      for (int off = 32; off; off >>= 1) { s += __shfl_down(s, off); c += __shfl_down(c, off); }
      if (lane == 0) { sc[o] = s; cc[o] = c + bb; }
    }
    return;
  }
  if (bx <= 8512) {
    // ---- fp32 -> bf16 conversion + row norms
    const float* src; u16* dst; float* nrm;
    if (bx <= 8192) {
      int row = (bx - 1) * 4 + wave;
      src = x + (size_t)row * LATENT; dst = xb + (size_t)row * LATENT; nrm = xxb + row;
    } else {
      int r = (bx - 8193) * 4 + wave;
      if (r < NSUP) { src = sup + (size_t)r * LATENT; dst = sups + (size_t)r * LATENT; nrm = xxsup + r; }
      else { int q = r - NSUP; src = sub + (size_t)q * LATENT; dst = subs + (size_t)q * LATENT; nrm = yys + q; }
    }
    const float* s = src + lane * 8;
    float4 v0 = ((const float4*)s)[0];
    float4 v1 = ((const float4*)s)[1];
    float ss = v0.x*v0.x + v0.y*v0.y + v0.z*v0.z + v0.w*v0.w
             + v1.x*v1.x + v1.y*v1.y + v1.z*v1.z + v1.w*v1.w;
    uint4 o;
    o.x = (unsigned)f2bf(v0.x) | ((unsigned)f2bf(v0.y) << 16);
    o.y = (unsigned)f2bf(v0.z) | ((unsigned)f2bf(v0.w) << 16);
    o.z = (unsigned)f2bf(v1.x) | ((unsigned)f2bf(v1.y) << 16);
    o.w = (unsigned)f2bf(v1.z) | ((unsigned)f2bf(v1.w) << 16);
    *((uint4*)(dst + lane * 8)) = o;
    for (int off = 32; off; off >>= 1) ss += __shfl_down(ss, off);
    if (lane == 0) *nrm = ss;
    return;
  }
  if (bx <= 8640) {
    // ---- Mt build (verified): mb -> (og, kh)
    int mb = bx - 8513;
    int k  = (mb & 1) * 256 + t;
    int o0 = (mb >> 1) * 8;
    if (o0 >= 400) {
      for (int oo = 0; oo < 8; oo++) Mt[(size_t)(o0 + oo) * LATENT + k] = 0;
      return;
    }
    const float* P; const float* W; int n, ow, sh;
    if (o0 < 200) { P = sup; W = W1; n = NSUP;  ow = o0; sh = 8; }
    else          { P = sub; W = W2; n = NSUB;  ow = o0 - 200; sh = 10; }
    float* lw = shmem;
    for (int idx = t; idx < 8 * n; idx += 256) {
      int oo = idx >> sh, j = idx & (n - 1);
      lw[oo * 1024 + j] = W[(size_t)(ow + oo) * n + j];
    }
    __syncthreads();
    float a[8] = {};
    for (int j = 0; j < n; j += 16) {
      float pv[16];
#pragma unroll
      for (int u = 0; u < 16; u++) pv[u] = P[(size_t)(j + u) * LATENT + k];
#pragma unroll
      for (int u = 0; u < 16; u++) {
#pragma unroll
        for (int oo = 0; oo < 8; oo++) a[oo] += pv[u] * lw[oo * 1024 + j + u];
      }
    }
#pragma unroll
    for (int oo = 0; oo < 8; oo++) Mt[(size_t)(o0 + oo) * LATENT + k] = f2bf(-2.f * a[oo]);
    return;
  }
  if (bx <= 8777) {
    int i = (bx - 8641) * 256 + t;
    if (i < BATCH + NSUP + 2 * NSUB) minbuf[i] = 0x7F800000u;
    return;
  }
  if (t < 4) out4[t] = 0.f;
  if (t == 4) *done = 0u;
}

// =================== KERNEL 2: all GEMM-shaped work + fused finisher ===================
// bx [0,3072): x-GEMM tiles. cb = bx%12 (panel), by = bx/12 (row tile).
//   cb<4: classifier epilogue (writes out);  cb>=4: sub-distance mins.
// bx [3072,3088): sup(256) x sub(1024) distance tiles (r3/r4 mins).
// All blocks: fence + done-count; last block reduces r1..r4 into out4.
__global__ __launch_bounds__(256) void k_main(const u16* __restrict__ xb,
    const u16* __restrict__ Bext, const float* __restrict__ xxb,
    const float* __restrict__ xxsup, const float* __restrict__ yys,
    const float* __restrict__ sc, const float* __restrict__ cc,
    const u16* __restrict__ sups, const u16* __restrict__ subs,
    float* __restrict__ out, float* __restrict__ out4,
    unsigned int* __restrict__ rowmin, unsigned int* __restrict__ colx,
    unsigned int* __restrict__ colsup, unsigned int* __restrict__ done) {
  __shared__ __align__(16) u16 lA[128 * 64];
  __shared__ __align__(16) u16 lB[128 * 64];
  int bx = blockIdx.x, t = threadIdx.x, wave = t >> 6, lane = t & 63;
  int l16 = lane & 15, qq = lane >> 4;
  int wm = (wave >> 1) * 64, wn = (wave & 1) * 64;

  const u16* Ab; const u16* Bb;
  int cb, isSup; size_t arow0;
  if (bx < 3072) {
    cb = bx % 12; arow0 = (size_t)(bx / 12) * 128; isSup = 0;
    Ab = xb + arow0 * LATENT; Bb = Bext + (size_t)cb * 128 * LATENT;
  } else {
    int s2 = bx - 3072;
    cb = s2 & 7; arow0 = (size_t)(s2 >> 3) * 128; isSup = 1;
    Ab = sups + arow0 * LATENT; Bb = subs + (size_t)cb * 128 * LATENT;
  }

  // ---- verified 128x128 K-loop (global_load_lds staging, pre-swizzled source)
  floatx4 acc[4][4] = {};
  int sq = (lane & 7) ^ (lane >> 3);
  int soff[4]; u16 *dA[4], *dB[4];
#pragma unroll
  for (int i = 0; i < 4; i++) {
    int s = i * 256 + t;
    soff[i] = (s >> 3) * LATENT + sq * 8;
    int sbase = (i * 256 + wave * 64) * 8;
    dA[i] = lA + sbase; dB[i] = lB + sbase;
  }
  for (int k0 = 0; k0 < LATENT; k0 += 64) {
#pragma unroll
    for (int i = 0; i < 4; i++) gload16(Ab + soff[i] + k0, dA[i]);
#pragma unroll
    for (int i = 0; i < 4; i++) gload16(Bb + soff[i] + k0, dB[i]);
    __syncthreads();
#pragma unroll
    for (int ks = 0; ks < 2; ks++) {
      bf16x8 af[4], bvv[4];
      int sw = ((ks * 4 + qq) ^ (l16 & 7)) * 8;
#pragma unroll
      for (int f = 0; f < 4; f++) {
        af[f]  = *(const bf16x8*)(lA + (wm + f * 16 + l16) * 64 + sw);
        bvv[f] = *(const bf16x8*)(lB + (wn + f * 16 + l16) * 64 + sw);
      }
#pragma unroll
      for (int fm = 0; fm < 4; fm++)
#pragma unroll
        for (int fn = 0; fn < 4; fn++)
          acc[fm][fn] = mfma_bf16(af[fm], bvv[fn], acc[fm][fn]);
    }
    __syncthreads();
  }

  // ---- epilogues
  if (!isSup && cb < 4) {
    // classifier heads: out = acc + xx*sc + cc  (cols cb*128.., valid < 400)
    int colb = cb * 128 + wn + l16;
#pragma unroll
    for (int fn = 0; fn < 4; fn++) {
      int c = colb + fn * 16;
      if (c < 400) {
        float scv = sc[c], ccv = cc[c];
#pragma unroll
        for (int fm = 0; fm < 4; fm++)
#pragma unroll
          for (int r = 0; r < 4; r++) {
            size_t row = arow0 + wm + fm * 16 + qq * 4 + r;
            float v = acc[fm][fn][r] + xxb[row] * scv + ccv;
            size_t idx = (c < 200) ? (SUP_OFF + row * NOUT + c)
                                   : (row * NOUT + (c - 200));
            out[idx] = v;
          }
      }
    }
  } else {
    // distance mins: d = xx - 2*acc + yy
    const float* xxsrc = (isSup ? xxsup : xxb) + arow0;
    const float* yyb   = yys + (isSup ? cb * 128 : (cb - 4) * 128);
    unsigned int* rmptr   = (isSup ? rowmin + BATCH : rowmin) + arow0;
    unsigned int* colatom = isSup ? (colsup + cb * 128) : (colx + (cb - 4) * 128);
    int colo = wn + l16;
    float yv[4];
#pragma unroll
    for (int fn = 0; fn < 4; fn++) yv[fn] = yyb[colo + fn * 16];
    float cmin[4] = {3.4e38f, 3.4e38f, 3.4e38f, 3.4e38f};
#pragma unroll
    for (int fm = 0; fm < 4; fm++) {
#pragma unroll
      for (int r = 0; r < 4; r++) {
        float xvv = xxsrc[wm + fm * 16 + qq * 4 + r];
        float rmin = 3.4e38f;
#pragma unroll
        for (int fn = 0; fn < 4; fn++) {
          float d = xvv - 2.0f * acc[fm][fn][r] + yv[fn];
          rmin = fminf(rmin, d);
          cmin[fn] = fminf(cmin[fn], d);
        }
        for (int off = 1; off < 16; off <<= 1) rmin = fminf(rmin, __shfl_xor(rmin, off));
        if (l16 == 0) atomicMin(rmptr + wm + fm * 16 + qq * 4 + r, __float_as_uint(rmin));
      }
    }
#pragma unroll
    for (int fn = 0; fn < 4; fn++) {
      float v = cmin[fn];
      v = fminf(v, __shfl_xor(v, 16));
      v = fminf(v, __shfl_xor(v, 32));
      if (qq == 0) atomicMin(colatom + colo + fn * 16, __float_as_uint(v));
    }
  }

  // ---- fused finisher: last block reduces the four means
  __threadfence();                 // release our atomicMin results
  __shared__ unsigned int lastf;
  if (t == 0) lastf = (atomicAdd(done, 1u) == (unsigned)(TOTAL_B - 1));
  __syncthreads();
  if (lastf) {
    __threadfence();               // acquire everyone else's results
    float* red = (float*)lA;
#pragma unroll 1
    for (int slot = 0; slot < 4; slot++) {
      const unsigned int* src; int n; float scale;
      if (slot == 0)      { src = colx;           n = NSUB;  scale = 1.f / NSUB;  }
      else if (slot == 1) { src = rowmin;         n = BATCH; scale = 1.f / BATCH; }
      else if (slot == 2) { src = rowmin + BATCH; n = NSUP;  scale = 1.f / NSUP;  }
      else                { src = colsup;         n = NSUB;  scale = 1.f / NSUB;  }
      float s = 0.f;
      for (int i = t; i < n; i += 256)
        s += __uint_as_float(__hip_atomic_load((unsigned int*)(src + i),
                             __ATOMIC_RELAXED, __HIP_MEMORY_SCOPE_AGENT));
      for (int off = 32; off; off >>= 1) s += __shfl_down(s, off);
      if ((t & 63) == 0) red[t >> 6] = s;
      __syncthreads();
      if (t == 0) out4[slot] = (red[0] + red[1] + red[2] + red[3]) * scale;
      __syncthreads();
    }
  }
}

extern "C" void kernel_launch(void* const* d_in, const int* in_sizes, int n_in,
                              void* d_out, int out_size, void* d_ws, size_t ws_size,
                              hipStream_t stream) {
  const float* x   = (const float*)d_in[0];
  const float* sup = (const float*)d_in[1];
  const float* sub = (const float*)d_in[2];
  const float* W1  = (const float*)d_in[3];
  const float* b1  = (const float*)d_in[4];
  const float* W2  = (const float*)d_in[5];
  const float* b2  = (const float*)d_in[6];
  float* out = (float*)d_out;

  char* p = (char*)d_ws;
  u16* Bext  = (u16*)p;            p += (size_t)(512 + NSUB) * LATENT * 2; // Mt(512) ++ subs(1024)
  u16* Mt    = Bext;
  u16* subs  = Bext + (size_t)512 * LATENT;
  u16* sups  = (u16*)p;            p += (size_t)NSUP * LATENT * 2;
  float* xxsup = (float*)p;        p += NSUP * 4;
  float* yys   = (float*)p;        p += NSUB * 4;
  float* sc    = (float*)p;        p += 512 * 4;
  float* cc    = (float*)p;        p += 512 * 4;
  unsigned int* rowmin = (unsigned int*)p; p += (size_t)(BATCH + NSUP) * 4;
  unsigned int* colx   = (unsigned int*)p; p += (size_t)NSUB * 4;
  unsigned int* colsup = (unsigned int*)p; p += (size_t)NSUB * 4;
  u16* xbuf    = (u16*)p;          p += (size_t)BATCH * LATENT * 2;   // 33.5 MB
  float* xxb   = (float*)p;        p += (size_t)BATCH * 4;

  unsigned int* done = (unsigned int*)(cc + 504);  // unused tail of cc (only [0,400) used)
  float* out4 = out + 2 * SUP_OFF;

  hipLaunchKernelGGL(k_prep, dim3(8779), dim3(256), 0, stream,
                     x, sup, sub, W1, b1, W2, b2, xbuf, xxb, sups, subs,
                     xxsup, yys, Mt, sc, cc, rowmin, out4, done);
  hipLaunchKernelGGL(k_main, dim3(TOTAL_B), dim3(256), 0, stream,
                     xbuf, Bext, xxb, xxsup, yys, sc, cc, sups, subs,
                     out, out4, rowmin, colx, colsup, done);
}

// Round 5
// 285.450 us; speedup vs baseline: 3.8815x; 3.8815x over previous
//
#include <hip/hip_runtime.h>
#include <stdint.h>

#define BATCH   32768
#define NSUP    256
#define NSUB    1024
#define LATENT  512
#define NOUT    200
#define SUP_OFF ((size_t)BATCH * NOUT)  // sup_out offset in d_out

typedef unsigned short u16;
typedef __attribute__((ext_vector_type(8))) __bf16 bf16x8;
typedef __attribute__((ext_vector_type(4))) float  floatx4;

typedef const __attribute__((address_space(1))) void* gptr_t;
typedef __attribute__((address_space(3))) void* sptr_t;

__device__ __forceinline__ void gload16(const void* g, void* l) {
  __builtin_amdgcn_global_load_lds((gptr_t)g, (sptr_t)l, 16, 0, 0);
}

__device__ __forceinline__ floatx4 mfma_bf16(bf16x8 a, bf16x8 b, floatx4 c) {
  return __builtin_amdgcn_mfma_f32_16x16x32_bf16(a, b, c, 0, 0, 0);
}

__device__ __forceinline__ u16 f2bf(float f) {
  unsigned int u = __float_as_uint(f);
  u += 0x7FFFu + ((u >> 16) & 1u);   // RNE; inputs finite
  return (u16)(u >> 16);
}

// ---------------- setup: cvt x + sup + sub -> bf16 + norms; init mins; zero r-slots
// bx [0,8192): x rows (4/block) -> xb + xxb. bx [8192,8512): sup/sub.
// bx [8512,8649): init 35072 min-uints; bx 8649: zero out4.
__global__ __launch_bounds__(256) void k_setup(const float* __restrict__ x,
    const float* __restrict__ sup, const float* __restrict__ sub,
    u16* __restrict__ xb, float* __restrict__ xxb,
    u16* __restrict__ sups, u16* __restrict__ subs,
    float* __restrict__ xxsup, float* __restrict__ yys,
    unsigned int* __restrict__ minbuf, float* __restrict__ out4) {
  int bx = blockIdx.x;
  int t  = threadIdx.x;
  if (bx >= 8512) {
    if (bx == 8649) { if (t < 4) out4[t] = 0.f; return; }
    int i = (bx - 8512) * 256 + t;
    if (i < BATCH + NSUP + 2 * NSUB) minbuf[i] = 0x7F800000u;
    return;
  }
  int row  = bx * 4 + (t >> 6);
  int lane = t & 63;
  const float* src; u16* dst; float* nrm;
  if (row < BATCH) {
    src = x + (size_t)row * LATENT; dst = xb + (size_t)row * LATENT; nrm = xxb + row;
  } else if (row < BATCH + NSUP) {
    int r = row - BATCH;
    src = sup + (size_t)r * LATENT; dst = sups + (size_t)r * LATENT; nrm = xxsup + r;
  } else {
    int r = row - BATCH - NSUP;
    src = sub + (size_t)r * LATENT; dst = subs + (size_t)r * LATENT; nrm = yys + r;
  }
  const float* s = src + lane * 8;
  float4 v0 = ((const float4*)s)[0];
  float4 v1 = ((const float4*)s)[1];
  float ss = v0.x*v0.x + v0.y*v0.y + v0.z*v0.z + v0.w*v0.w
           + v1.x*v1.x + v1.y*v1.y + v1.z*v1.z + v1.w*v1.w;
  uint4 o;
  o.x = (unsigned)f2bf(v0.x) | ((unsigned)f2bf(v0.y) << 16);
  o.y = (unsigned)f2bf(v0.z) | ((unsigned)f2bf(v0.w) << 16);
  o.z = (unsigned)f2bf(v1.x) | ((unsigned)f2bf(v1.y) << 16);
  o.w = (unsigned)f2bf(v1.z) | ((unsigned)f2bf(v1.w) << 16);
  *((uint4*)(dst + lane * 8)) = o;
  for (int off = 32; off; off >>= 1) ss += __shfl_down(ss, off);
  if (lane == 0) *nrm = ss;
}

// ---------------- Mt build + wprep constants (round-3 verified)
// bx [0,128): Mt[o][k] = -2 sum_j W[o,j] P[j,k] (8 outs/block; rows 400..511 zero)
// bx [128,228): sc/cc per output, one wave per output.
__global__ __launch_bounds__(256) void k_mt_w(const float* __restrict__ sup,
    const float* __restrict__ sub, const float* __restrict__ W1,
    const float* __restrict__ b1, const float* __restrict__ W2,
    const float* __restrict__ b2, const float* __restrict__ xxsup,
    const float* __restrict__ yys, u16* __restrict__ Mt,
    float* __restrict__ sc, float* __restrict__ cc) {
  int bx = blockIdx.x;
  if (bx >= 128) {
    int wave = threadIdx.x >> 6, lane = threadIdx.x & 63;
    int o = (bx - 128) * 4 + wave;
    if (o >= 400) return;
    int n; const float* Wr; const float* yy;
    if (o < 200) { n = NSUP; Wr = W1 + (size_t)o * NSUP; yy = xxsup; }
    else         { n = NSUB; Wr = W2 + (size_t)(o - 200) * NSUB; yy = yys; }
    float s = 0.f, c = 0.f;
    for (int j = lane; j < n; j += 64) { float w = Wr[j]; s += w; c += w * yy[j]; }
    for (int off = 32; off; off >>= 1) { s += __shfl_down(s, off); c += __shfl_down(c, off); }
    if (lane == 0) { sc[o] = s; cc[o] = c + ((o < 200) ? b1[o] : b2[o - 200]); }
    return;
  }
  __shared__ float lw[8 * 1024];
  int k  = (bx & 1) * 256 + threadIdx.x;
  int o0 = (bx >> 1) * 8;
  if (o0 >= 400) {
    for (int oo = 0; oo < 8; oo++) Mt[(size_t)(o0 + oo) * LATENT + k] = 0;
    return;
  }
  const float* P; const float* W; int n, ow, sh;
  if (o0 < 200) { P = sup; W = W1; n = NSUP;  ow = o0; sh = 8; }
  else          { P = sub; W = W2; n = NSUB;  ow = o0 - 200; sh = 10; }
  for (int idx = threadIdx.x; idx < 8 * n; idx += 256) {
    int oo = idx >> sh, j = idx & (n - 1);
    lw[oo * 1024 + j] = W[(size_t)(ow + oo) * n + j];
  }
  __syncthreads();
  float a[8] = {};
  for (int j = 0; j < n; j += 16) {
    float pv[16];
#pragma unroll
    for (int u = 0; u < 16; u++) pv[u] = P[(size_t)(j + u) * LATENT + k];
#pragma unroll
    for (int u = 0; u < 16; u++) {
#pragma unroll
      for (int oo = 0; oo < 8; oo++) a[oo] += pv[u] * lw[oo * 1024 + j + u];
    }
  }
#pragma unroll
  for (int oo = 0; oo < 8; oo++) Mt[(size_t)(o0 + oo) * LATENT + k] = f2bf(-2.f * a[oo]);
}

// ---------------- main GEMM kernel: round-3-verified 128x128 K-loop.
// bx [0,3072): x-GEMM tiles, XCD-swizzled: xcd=bx&7 owns rowtiles [xcd*32,xcd*32+32)
//   x all 12 panels -> A tiles fetched ~once per XCD, all B panels L2-resident.
//   panel<4: classifier epilogue; panel>=4: sub-distance mins.
// bx [3072,3088): sup(256) x sub(1024) distance tiles (r3/r4 mins).
// NO fences, NO done counter (round-4 lesson: per-block agent fences flush L2).
__global__ __launch_bounds__(256) void k_main(const u16* __restrict__ xb,
    const u16* __restrict__ Bext, const float* __restrict__ xxb,
    const float* __restrict__ xxsup, const float* __restrict__ yys,
    const float* __restrict__ sc, const float* __restrict__ cc,
    const u16* __restrict__ sups, const u16* __restrict__ subs,
    float* __restrict__ out, unsigned int* __restrict__ rowmin,
    unsigned int* __restrict__ colx, unsigned int* __restrict__ colsup) {
  __shared__ __align__(16) u16 lA[128 * 64];
  __shared__ __align__(16) u16 lB[128 * 64];
  int bx = blockIdx.x, t = threadIdx.x, wave = t >> 6, lane = t & 63;
  int l16 = lane & 15, qq = lane >> 4;
  int wm = (wave >> 1) * 64, wn = (wave & 1) * 64;

  const u16* Ab; const u16* Bb;
  int cb, isSup; size_t arow0;
  if (bx < 3072) {
    int xcd = bx & 7, local = bx >> 3;
    int rowt = xcd * 32 + local / 12;
    cb = local % 12;
    arow0 = (size_t)rowt * 128; isSup = 0;
    Ab = xb + arow0 * LATENT; Bb = Bext + (size_t)cb * 128 * LATENT;
  } else {
    int s2 = bx - 3072;
    cb = s2 & 7; arow0 = (size_t)(s2 >> 3) * 128; isSup = 1;
    Ab = sups + arow0 * LATENT; Bb = subs + (size_t)cb * 128 * LATENT;
  }

  // ---- verified 128x128 K-loop (global_load_lds staging, pre-swizzled source)
  floatx4 acc[4][4] = {};
  int sq = (lane & 7) ^ (lane >> 3);
  int soff[4]; u16 *dA[4], *dB[4];
#pragma unroll
  for (int i = 0; i < 4; i++) {
    int s = i * 256 + t;
    soff[i] = (s >> 3) * LATENT + sq * 8;
    int sbase = (i * 256 + wave * 64) * 8;
    dA[i] = lA + sbase; dB[i] = lB + sbase;
  }
  for (int k0 = 0; k0 < LATENT; k0 += 64) {
#pragma unroll
    for (int i = 0; i < 4; i++) gload16(Ab + soff[i] + k0, dA[i]);
#pragma unroll
    for (int i = 0; i < 4; i++) gload16(Bb + soff[i] + k0, dB[i]);
    __syncthreads();
#pragma unroll
    for (int ks = 0; ks < 2; ks++) {
      bf16x8 af[4], bvv[4];
      int sw = ((ks * 4 + qq) ^ (l16 & 7)) * 8;
#pragma unroll
      for (int f = 0; f < 4; f++) {
        af[f]  = *(const bf16x8*)(lA + (wm + f * 16 + l16) * 64 + sw);
        bvv[f] = *(const bf16x8*)(lB + (wn + f * 16 + l16) * 64 + sw);
      }
#pragma unroll
      for (int fm = 0; fm < 4; fm++)
#pragma unroll
        for (int fn = 0; fn < 4; fn++)
          acc[fm][fn] = mfma_bf16(af[fm], bvv[fn], acc[fm][fn]);
    }
    __syncthreads();
  }

  // ---- epilogues (round-3 verified)
  if (!isSup && cb < 4) {
    // classifier heads: out = acc + xx*sc + cc  (cols cb*128.., valid < 400)
    int colb = cb * 128 + wn + l16;
#pragma unroll
    for (int fn = 0; fn < 4; fn++) {
      int c = colb + fn * 16;
      if (c < 400) {
        float scv = sc[c], ccv = cc[c];
#pragma unroll
        for (int fm = 0; fm < 4; fm++)
#pragma unroll
          for (int r = 0; r < 4; r++) {
            size_t row = arow0 + wm + fm * 16 + qq * 4 + r;
            float v = acc[fm][fn][r] + xxb[row] * scv + ccv;
            size_t idx = (c < 200) ? (SUP_OFF + row * NOUT + c)
                                   : (row * NOUT + (c - 200));
            out[idx] = v;
          }
      }
    }
  } else {
    // distance mins: d = xx - 2*acc + yy
    const float* xxsrc = (isSup ? xxsup : xxb) + arow0;
    const float* yyb   = yys + (isSup ? cb * 128 : (cb - 4) * 128);
    unsigned int* rmptr   = (isSup ? rowmin + BATCH : rowmin) + arow0;
    unsigned int* colatom = isSup ? (colsup + cb * 128) : (colx + (cb - 4) * 128);
    int colo = wn + l16;
    float yv[4];
#pragma unroll
    for (int fn = 0; fn < 4; fn++) yv[fn] = yyb[colo + fn * 16];
    float cmin[4] = {3.4e38f, 3.4e38f, 3.4e38f, 3.4e38f};
#pragma unroll
    for (int fm = 0; fm < 4; fm++) {
#pragma unroll
      for (int r = 0; r < 4; r++) {
        float xvv = xxsrc[wm + fm * 16 + qq * 4 + r];
        float rmin = 3.4e38f;
#pragma unroll
        for (int fn = 0; fn < 4; fn++) {
          float d = xvv - 2.0f * acc[fm][fn][r] + yv[fn];
          rmin = fminf(rmin, d);
          cmin[fn] = fminf(cmin[fn], d);
        }
        for (int off = 1; off < 16; off <<= 1) rmin = fminf(rmin, __shfl_xor(rmin, off));
        if (l16 == 0) atomicMin(rmptr + wm + fm * 16 + qq * 4 + r, __float_as_uint(rmin));
      }
    }
#pragma unroll
    for (int fn = 0; fn < 4; fn++) {
      float v = cmin[fn];
      v = fminf(v, __shfl_xor(v, 16));
      v = fminf(v, __shfl_xor(v, 32));
      if (qq == 0) atomicMin(colatom + colo + fn * 16, __float_as_uint(v));
    }
  }
}

// ---------------- parallel means of mins -> r1,r2,r3,r4 (atomicAdd partials)
__global__ __launch_bounds__(256) void k_final2(const unsigned int* __restrict__ rowmin,
    const unsigned int* __restrict__ colx, const unsigned int* __restrict__ colsup,
    float* __restrict__ out4) {
  int bx = blockIdx.x, t = threadIdx.x;
  const unsigned int* src; int n; float scale; int slot;
  if (bx < 32)      { src = rowmin + bx * 1024; n = 1024; scale = 1.f / BATCH; slot = 1; }
  else if (bx == 32){ src = colx;               n = 1024; scale = 1.f / NSUB;  slot = 0; }
  else if (bx == 33){ src = rowmin + BATCH;     n = 256;  scale = 1.f / NSUP;  slot = 2; }
  else              { src = colsup;             n = 1024; scale = 1.f / NSUB;  slot = 3; }
  float s = 0.f;
  for (int i = t; i < n; i += 256) s += __uint_as_float(src[i]);
  __shared__ float red[4];
  for (int off = 32; off; off >>= 1) s += __shfl_down(s, off);
  if ((t & 63) == 0) red[t >> 6] = s;
  __syncthreads();
  if (t == 0) atomicAdd(out4 + slot, (red[0] + red[1] + red[2] + red[3]) * scale);
}

extern "C" void kernel_launch(void* const* d_in, const int* in_sizes, int n_in,
                              void* d_out, int out_size, void* d_ws, size_t ws_size,
                              hipStream_t stream) {
  const float* x   = (const float*)d_in[0];
  const float* sup = (const float*)d_in[1];
  const float* sub = (const float*)d_in[2];
  const float* W1  = (const float*)d_in[3];
  const float* b1  = (const float*)d_in[4];
  const float* W2  = (const float*)d_in[5];
  const float* b2  = (const float*)d_in[6];
  float* out = (float*)d_out;

  char* p = (char*)d_ws;
  u16* Bext  = (u16*)p;            p += (size_t)(512 + NSUB) * LATENT * 2; // Mt(512) ++ subs(1024)
  u16* Mt    = Bext;
  u16* subs  = Bext + (size_t)512 * LATENT;
  u16* sups  = (u16*)p;            p += (size_t)NSUP * LATENT * 2;
  float* xxsup = (float*)p;        p += NSUP * 4;
  float* yys   = (float*)p;        p += NSUB * 4;
  float* sc    = (float*)p;        p += 512 * 4;
  float* cc    = (float*)p;        p += 512 * 4;
  unsigned int* rowmin = (unsigned int*)p; p += (size_t)(BATCH + NSUP) * 4;
  unsigned int* colx   = (unsigned int*)p; p += (size_t)NSUB * 4;
  unsigned int* colsup = (unsigned int*)p; p += (size_t)NSUB * 4;
  u16* xbuf    = (u16*)p;          p += (size_t)BATCH * LATENT * 2;   // 33.5 MB
  float* xxb   = (float*)p;        p += (size_t)BATCH * 4;

  float* out4 = out + 2 * SUP_OFF;

  hipLaunchKernelGGL(k_setup, dim3(8650), dim3(256), 0, stream,
                     x, sup, sub, xbuf, xxb, sups, subs, xxsup, yys, rowmin, out4);
  hipLaunchKernelGGL(k_mt_w, dim3(228), dim3(256), 0, stream,
                     sup, sub, W1, b1, W2, b2, xxsup, yys, Mt, sc, cc);
  hipLaunchKernelGGL(k_main, dim3(3088), dim3(256), 0, stream,
                     xbuf, Bext, xxb, xxsup, yys, sc, cc, sups, subs,
                     out, rowmin, colx, colsup);
  hipLaunchKernelGGL(k_final2, dim3(35), dim3(256), 0, stream, rowmin, colx, colsup, out4);
}

// Round 6
// 230.600 us; speedup vs baseline: 4.8048x; 1.2379x over previous
//
#include <hip/hip_runtime.h>
#include <stdint.h>

#define BATCH   32768
#define NSUP    256
#define NSUB    1024
#define LATENT  512
#define NOUT    200
#define SUP_OFF ((size_t)BATCH * NOUT)  // sup_out offset in d_out

typedef unsigned short u16;
typedef __attribute__((ext_vector_type(8))) __bf16 bf16x8;
typedef __attribute__((ext_vector_type(4))) float  floatx4;

typedef const __attribute__((address_space(1))) void* gptr_t;
typedef __attribute__((address_space(3))) void* sptr_t;

__device__ __forceinline__ void gload16(const void* g, void* l) {
  __builtin_amdgcn_global_load_lds((gptr_t)g, (sptr_t)l, 16, 0, 0);
}

__device__ __forceinline__ floatx4 mfma_bf16(bf16x8 a, bf16x8 b, floatx4 c) {
  return __builtin_amdgcn_mfma_f32_16x16x32_bf16(a, b, c, 0, 0, 0);
}

__device__ __forceinline__ u16 f2bf(float f) {
  unsigned int u = __float_as_uint(f);
  u += 0x7FFFu + ((u >> 16) & 1u);   // RNE; inputs finite
  return (u16)(u >> 16);
}

// =============== setup2: Mt build (independent, latency-bound) FIRST, overlapped
// with the BW-bound conversions. No dependency between the two families.
// bx [0,256)    : Mt[o][k] = -2 sum_j W[o,j] P[j,k]; block = (o-group of 8, k-quarter 128)
// bx [256,8768) : conversions, row = (bx-256)*4+wave: x -> xb/xxb, sup -> sups/xxsup,
//                 sub -> subs/yys
// bx [8768,8905): init 35072 min-slots; bx 8905: zero out4
__global__ __launch_bounds__(256) void k_setup2(const float* __restrict__ x,
    const float* __restrict__ sup, const float* __restrict__ sub,
    const float* __restrict__ W1, const float* __restrict__ W2,
    u16* __restrict__ xb, float* __restrict__ xxb,
    u16* __restrict__ sups, u16* __restrict__ subs,
    float* __restrict__ xxsup, float* __restrict__ yys,
    u16* __restrict__ Mt, unsigned int* __restrict__ minbuf,
    float* __restrict__ out4) {
  __shared__ float lw[8 * 1024];
  int bx = blockIdx.x, t = threadIdx.x;
  if (bx < 256) {
    // ---- Mt build: 64 o-groups x 4 k-quarters; thread = (k-col, out-half of 4)
    int og = bx >> 2, kq = bx & 3;
    int o0 = og * 8;
    int kk = t & 127, oh = t >> 7;
    int k  = kq * 128 + kk;
    if (o0 >= 400) {
#pragma unroll
      for (int oo = 0; oo < 4; oo++) Mt[(size_t)(o0 + oh * 4 + oo) * LATENT + k] = 0;
      return;
    }
    const float* P; const float* W; int n, ow, sh;
    if (o0 < 200) { P = sup; W = W1; n = NSUP;  ow = o0; sh = 8; }
    else          { P = sub; W = W2; n = NSUB;  ow = o0 - 200; sh = 10; }
    for (int idx = t; idx < 8 * n; idx += 256) {
      int oo = idx >> sh, j = idx & (n - 1);
      lw[oo * 1024 + j] = W[(size_t)(ow + oo) * n + j];
    }
    __syncthreads();
    float a[4] = {};
    for (int j = 0; j < n; j += 16) {
      float pv[16];
#pragma unroll
      for (int u = 0; u < 16; u++) pv[u] = P[(size_t)(j + u) * LATENT + k];
#pragma unroll
      for (int u = 0; u < 16; u++) {
#pragma unroll
        for (int oo = 0; oo < 4; oo++) a[oo] += pv[u] * lw[(oh * 4 + oo) * 1024 + j + u];
      }
    }
#pragma unroll
    for (int oo = 0; oo < 4; oo++)
      Mt[(size_t)(o0 + oh * 4 + oo) * LATENT + k] = f2bf(-2.f * a[oo]);
    return;
  }
  if (bx >= 8768) {
    if (bx == 8905) { if (t < 4) out4[t] = 0.f; return; }
    int i = (bx - 8768) * 256 + t;
    if (i < BATCH + NSUP + 2 * NSUB) minbuf[i] = 0x7F800000u;
    return;
  }
  // ---- conversions + row norms
  int row  = (bx - 256) * 4 + (t >> 6);
  int lane = t & 63;
  const float* src; u16* dst; float* nrm;
  if (row < BATCH) {
    src = x + (size_t)row * LATENT; dst = xb + (size_t)row * LATENT; nrm = xxb + row;
  } else if (row < BATCH + NSUP) {
    int r = row - BATCH;
    src = sup + (size_t)r * LATENT; dst = sups + (size_t)r * LATENT; nrm = xxsup + r;
  } else {
    int r = row - BATCH - NSUP;
    src = sub + (size_t)r * LATENT; dst = subs + (size_t)r * LATENT; nrm = yys + r;
  }
  const float* s = src + lane * 8;
  float4 v0 = ((const float4*)s)[0];
  float4 v1 = ((const float4*)s)[1];
  float ss = v0.x*v0.x + v0.y*v0.y + v0.z*v0.z + v0.w*v0.w
           + v1.x*v1.x + v1.y*v1.y + v1.z*v1.z + v1.w*v1.w;
  uint4 o;
  o.x = (unsigned)f2bf(v0.x) | ((unsigned)f2bf(v0.y) << 16);
  o.y = (unsigned)f2bf(v0.z) | ((unsigned)f2bf(v0.w) << 16);
  o.z = (unsigned)f2bf(v1.x) | ((unsigned)f2bf(v1.y) << 16);
  o.w = (unsigned)f2bf(v1.z) | ((unsigned)f2bf(v1.w) << 16);
  *((uint4*)(dst + lane * 8)) = o;
  for (int off = 32; off; off >>= 1) ss += __shfl_down(ss, off);
  if (lane == 0) *nrm = ss;
}

// =============== k_w: sc/cc per output (needs xxsup/yys -> after k_setup2)
__global__ __launch_bounds__(256) void k_w(const float* __restrict__ W1,
    const float* __restrict__ b1, const float* __restrict__ W2,
    const float* __restrict__ b2, const float* __restrict__ xxsup,
    const float* __restrict__ yys, float* __restrict__ sc, float* __restrict__ cc) {
  int wave = threadIdx.x >> 6, lane = threadIdx.x & 63;
  int o = blockIdx.x * 4 + wave;
  if (o >= 400) return;
  int n; const float* Wr; const float* yy;
  if (o < 200) { n = NSUP; Wr = W1 + (size_t)o * NSUP; yy = xxsup; }
  else         { n = NSUB; Wr = W2 + (size_t)(o - 200) * NSUB; yy = yys; }
  float s = 0.f, c = 0.f;
  for (int j = lane; j < n; j += 64) { float w = Wr[j]; s += w; c += w * yy[j]; }
  for (int off = 32; off; off >>= 1) { s += __shfl_down(s, off); c += __shfl_down(c, off); }
  if (lane == 0) { sc[o] = s; cc[o] = c + ((o < 200) ? b1[o] : b2[o - 200]); }
}

// =============== main GEMM kernel: verified 128x128 K-loop.
// bx [0,16)    : sup(256) x sub(1024) distance tiles FIRST (no serial tail).
// bx [16,3088) : x-GEMM tiles, XCD-swizzled (xcd owns 32 contiguous rowtiles x 12 panels).
// launch_bounds(256,4): request 16 waves/CU residency (VGPR 112 <= 128 cap).
__global__ __launch_bounds__(256, 4) void k_main(const u16* __restrict__ xb,
    const u16* __restrict__ Bext, const float* __restrict__ xxb,
    const float* __restrict__ xxsup, const float* __restrict__ yys,
    const float* __restrict__ sc, const float* __restrict__ cc,
    const u16* __restrict__ sups, const u16* __restrict__ subs,
    float* __restrict__ out, unsigned int* __restrict__ rowmin,
    unsigned int* __restrict__ colx, unsigned int* __restrict__ colsup) {
  __shared__ __align__(16) u16 lA[128 * 64];
  __shared__ __align__(16) u16 lB[128 * 64];
  int bx = blockIdx.x, t = threadIdx.x, wave = t >> 6, lane = t & 63;
  int l16 = lane & 15, qq = lane >> 4;
  int wm = (wave >> 1) * 64, wn = (wave & 1) * 64;

  const u16* Ab; const u16* Bb;
  int cb, isSup; size_t arow0;
  if (bx < 16) {
    cb = bx & 7; arow0 = (size_t)(bx >> 3) * 128; isSup = 1;
    Ab = sups + arow0 * LATENT; Bb = subs + (size_t)cb * 128 * LATENT;
  } else {
    int g = bx - 16;
    int xcd = g & 7, local = g >> 3;
    int rowt = xcd * 32 + local / 12;
    cb = local % 12;
    arow0 = (size_t)rowt * 128; isSup = 0;
    Ab = xb + arow0 * LATENT; Bb = Bext + (size_t)cb * 128 * LATENT;
  }

  // ---- verified 128x128 K-loop (global_load_lds staging, pre-swizzled source)
  floatx4 acc[4][4] = {};
  int sq = (lane & 7) ^ (lane >> 3);
  int soff[4]; u16 *dA[4], *dB[4];
#pragma unroll
  for (int i = 0; i < 4; i++) {
    int s = i * 256 + t;
    soff[i] = (s >> 3) * LATENT + sq * 8;
    int sbase = (i * 256 + wave * 64) * 8;
    dA[i] = lA + sbase; dB[i] = lB + sbase;
  }
  for (int k0 = 0; k0 < LATENT; k0 += 64) {
#pragma unroll
    for (int i = 0; i < 4; i++) gload16(Ab + soff[i] + k0, dA[i]);
#pragma unroll
    for (int i = 0; i < 4; i++) gload16(Bb + soff[i] + k0, dB[i]);
    __syncthreads();
#pragma unroll
    for (int ks = 0; ks < 2; ks++) {
      bf16x8 af[4], bvv[4];
      int sw = ((ks * 4 + qq) ^ (l16 & 7)) * 8;
#pragma unroll
      for (int f = 0; f < 4; f++) {
        af[f]  = *(const bf16x8*)(lA + (wm + f * 16 + l16) * 64 + sw);
        bvv[f] = *(const bf16x8*)(lB + (wn + f * 16 + l16) * 64 + sw);
      }
#pragma unroll
      for (int fm = 0; fm < 4; fm++)
#pragma unroll
        for (int fn = 0; fn < 4; fn++)
          acc[fm][fn] = mfma_bf16(af[fm], bvv[fn], acc[fm][fn]);
    }
    __syncthreads();
  }

  // ---- epilogues (verified)
  if (!isSup && cb < 4) {
    int colb = cb * 128 + wn + l16;
#pragma unroll
    for (int fn = 0; fn < 4; fn++) {
      int c = colb + fn * 16;
      if (c < 400) {
        float scv = sc[c], ccv = cc[c];
#pragma unroll
        for (int fm = 0; fm < 4; fm++)
#pragma unroll
          for (int r = 0; r < 4; r++) {
            size_t row = arow0 + wm + fm * 16 + qq * 4 + r;
            float v = acc[fm][fn][r] + xxb[row] * scv + ccv;
            size_t idx = (c < 200) ? (SUP_OFF + row * NOUT + c)
                                   : (row * NOUT + (c - 200));
            out[idx] = v;
          }
      }
    }
  } else {
    const float* xxsrc = (isSup ? xxsup : xxb) + arow0;
    const float* yyb   = yys + (isSup ? cb * 128 : (cb - 4) * 128);
    unsigned int* rmptr   = (isSup ? rowmin + BATCH : rowmin) + arow0;
    unsigned int* colatom = isSup ? (colsup + cb * 128) : (colx + (cb - 4) * 128);
    int colo = wn + l16;
    float yv[4];
#pragma unroll
    for (int fn = 0; fn < 4; fn++) yv[fn] = yyb[colo + fn * 16];
    float cmin[4] = {3.4e38f, 3.4e38f, 3.4e38f, 3.4e38f};
#pragma unroll
    for (int fm = 0; fm < 4; fm++) {
#pragma unroll
      for (int r = 0; r < 4; r++) {
        float xvv = xxsrc[wm + fm * 16 + qq * 4 + r];
        float rmin = 3.4e38f;
#pragma unroll
        for (int fn = 0; fn < 4; fn++) {
          float d = xvv - 2.0f * acc[fm][fn][r] + yv[fn];
          rmin = fminf(rmin, d);
          cmin[fn] = fminf(cmin[fn], d);
        }
        for (int off = 1; off < 16; off <<= 1) rmin = fminf(rmin, __shfl_xor(rmin, off));
        if (l16 == 0) atomicMin(rmptr + wm + fm * 16 + qq * 4 + r, __float_as_uint(rmin));
      }
    }
#pragma unroll
    for (int fn = 0; fn < 4; fn++) {
      float v = cmin[fn];
      v = fminf(v, __shfl_xor(v, 16));
      v = fminf(v, __shfl_xor(v, 32));
      if (qq == 0) atomicMin(colatom + colo + fn * 16, __float_as_uint(v));
    }
  }
}

// =============== parallel means of mins -> r1,r2,r3,r4 (atomicAdd partials)
__global__ __launch_bounds__(256) void k_final2(const unsigned int* __restrict__ rowmin,
    const unsigned int* __restrict__ colx, const unsigned int* __restrict__ colsup,
    float* __restrict__ out4) {
  int bx = blockIdx.x, t = threadIdx.x;
  const unsigned int* src; int n; float scale; int slot;
  if (bx < 32)      { src = rowmin + bx * 1024; n = 1024; scale = 1.f / BATCH; slot = 1; }
  else if (bx == 32){ src = colx;               n = 1024; scale = 1.f / NSUB;  slot = 0; }
  else if (bx == 33){ src = rowmin + BATCH;     n = 256;  scale = 1.f / NSUP;  slot = 2; }
  else              { src = colsup;             n = 1024; scale = 1.f / NSUB;  slot = 3; }
  float s = 0.f;
  for (int i = t; i < n; i += 256) s += __uint_as_float(src[i]);
  __shared__ float red[4];
  for (int off = 32; off; off >>= 1) s += __shfl_down(s, off);
  if ((t & 63) == 0) red[t >> 6] = s;
  __syncthreads();
  if (t == 0) atomicAdd(out4 + slot, (red[0] + red[1] + red[2] + red[3]) * scale);
}

extern "C" void kernel_launch(void* const* d_in, const int* in_sizes, int n_in,
                              void* d_out, int out_size, void* d_ws, size_t ws_size,
                              hipStream_t stream) {
  const float* x   = (const float*)d_in[0];
  const float* sup = (const float*)d_in[1];
  const float* sub = (const float*)d_in[2];
  const float* W1  = (const float*)d_in[3];
  const float* b1  = (const float*)d_in[4];
  const float* W2  = (const float*)d_in[5];
  const float* b2  = (const float*)d_in[6];
  float* out = (float*)d_out;

  char* p = (char*)d_ws;
  u16* Bext  = (u16*)p;            p += (size_t)(512 + NSUB) * LATENT * 2; // Mt(512) ++ subs(1024)
  u16* Mt    = Bext;
  u16* subs  = Bext + (size_t)512 * LATENT;
  u16* sups  = (u16*)p;            p += (size_t)NSUP * LATENT * 2;
  float* xxsup = (float*)p;        p += NSUP * 4;
  float* yys   = (float*)p;        p += NSUB * 4;
  float* sc    = (float*)p;        p += 512 * 4;
  float* cc    = (float*)p;        p += 512 * 4;
  unsigned int* rowmin = (unsigned int*)p; p += (size_t)(BATCH + NSUP) * 4;
  unsigned int* colx   = (unsigned int*)p; p += (size_t)NSUB * 4;
  unsigned int* colsup = (unsigned int*)p; p += (size_t)NSUB * 4;
  u16* xbuf    = (u16*)p;          p += (size_t)BATCH * LATENT * 2;   // 33.5 MB
  float* xxb   = (float*)p;        p += (size_t)BATCH * 4;

  float* out4 = out + 2 * SUP_OFF;

  hipLaunchKernelGGL(k_setup2, dim3(8906), dim3(256), 0, stream,
                     x, sup, sub, W1, W2, xbuf, xxb, sups, subs, xxsup, yys,
                     Mt, rowmin, out4);
  hipLaunchKernelGGL(k_w, dim3(100), dim3(256), 0, stream,
                     W1, b1, W2, b2, xxsup, yys, sc, cc);
  hipLaunchKernelGGL(k_main, dim3(3088), dim3(256), 0, stream,
                     xbuf, Bext, xxb, xxsup, yys, sc, cc, sups, subs,
                     out, rowmin, colx, colsup);
  hipLaunchKernelGGL(k_final2, dim3(35), dim3(256), 0, stream, rowmin, colx, colsup, out4);
}